// Round 18
// baseline (209.952 us; speedup 1.0000x reference)
//
#include <hip/hip_runtime.h>
#include <hip/hip_bf16.h>
#include <math.h>

#define NB 256
#define NC 512
#define NP 196
#define NIT 32
#define PROWS 208          // LDS row count (13 tiles of 16); global panels store 196 rows/part
#define PR 196             // global panel rows per part
#define LSTR 72            // LDS short-row stride for 64-c slices
#define SFSTR 211

typedef __attribute__((ext_vector_type(8))) short bf16x8;
typedef __attribute__((ext_vector_type(4))) float f32x4;

__device__ __forceinline__ float sigf(float z){ return 1.0f/(1.0f+expf(-z)); }

__device__ __forceinline__ unsigned short f2bf(float x){
  return __bfloat16_as_ushort(__float2bfloat16(x));
}
__device__ __forceinline__ float bf2f(unsigned short h){
  union{float f; unsigned u;} v; v.u = ((unsigned)h)<<16; return v.f;
}
__device__ __forceinline__ double dshfl_xor(double v, int m){
  int lo = __shfl_xor(__double2loint(v), m);
  int hi = __shfl_xor(__double2hiint(v), m);
  return __hiloint2double(hi, lo);
}

// panel layout: hiT/loT [b][part8][PR][64]  (row-part = 128B contiguous)

// ---------------- transpose+convert+partial-pl (+ aud->bf16 on part==0) ----------------
__global__ __launch_bounds__(512) void convert4_kernel(
    const float* __restrict__ img, const float* __restrict__ aud,
    unsigned short* __restrict__ hiT, unsigned short* __restrict__ loT,
    unsigned short* __restrict__ aud_bf,
    double* __restrict__ ppl, double* __restrict__ pcs)   // [NB][8][196]
{
  const int bid = blockIdx.x;
  const int b = bid & 255, part = bid >> 8;     // parts of b share XCD (256%8==0)
  const int tid = threadIdx.x;
  const float* imgb = img + (size_t)b*NC*NP + (size_t)part*64*NP;
  __shared__ float sf[64*SFSTR];                // 54.0 KB
  __shared__ float s_aud[64];
  if (part == 0) aud_bf[b*NC + tid] = f2bf(aud[b*NC + tid]);   // 512 threads = NC
  if (tid < 64) s_aud[tid] = aud[b*NC + part*64 + tid];

  for (int j=tid; j<64*49; j+=512){
    int p4 = j % 49, c = j / 49;
    float4 v = *(const float4*)&imgb[(size_t)c*NP + p4*4];
    sf[c*SFSTR + p4*4+0]=v.x; sf[c*SFSTR + p4*4+1]=v.y;
    sf[c*SFSTR + p4*4+2]=v.z; sf[c*SFSTR + p4*4+3]=v.w;
  }
  __syncthreads();

  unsigned short* hp = hiT + (size_t)(b*8+part)*PR*64;
  unsigned short* lp = loT + (size_t)(b*8+part)*PR*64;
  for (int j=tid; j<PROWS*8; j+=512){
    int p = j>>3, o = j&7;
    unsigned hw[4], lw[4];
    double dot=0.0, sm=0.0;
    #pragma unroll
    for (int k2=0;k2<4;++k2){
      int c = o*8 + 2*k2;
      float x0 = (p<NP) ? sf[c*SFSTR + p]     : 0.f;
      float x1 = (p<NP) ? sf[(c+1)*SFSTR + p] : 0.f;
      unsigned short h0=f2bf(x0), h1=f2bf(x1);
      unsigned short l0=f2bf(x0-bf2f(h0)), l1=f2bf(x1-bf2f(h1));
      hw[k2] = (unsigned)h0 | ((unsigned)h1<<16);
      lw[k2] = (unsigned)l0 | ((unsigned)l1<<16);
      dot += (double)x0*(double)s_aud[c] + (double)x1*(double)s_aud[c+1];
      sm  += (double)x0 + (double)x1;
    }
    if (p < NP){   // only 196 real rows stored
      *(uint4*)&hp[p*64 + o*8] = *(uint4*)hw;
      *(uint4*)&lp[p*64 + o*8] = *(uint4*)lw;
    }
    dot += dshfl_xor(dot,1); dot += dshfl_xor(dot,2); dot += dshfl_xor(dot,4);
    sm  += dshfl_xor(sm,1);  sm  += dshfl_xor(sm,2);  sm  += dshfl_xor(sm,4);
    if (o==0 && p<NP){
      ppl[(size_t)(b*8+part)*NP + p] = dot;
      pcs[(size_t)(b*8+part)*NP + p] = sm;
    }
  }
}

// ---------------- fused Gram + all_logits: every block does BOTH (homogeneous) ----------------
// Block (b,h): gram col-half h + sim n-half h, sharing one staged panel per K-slice.
__global__ __launch_bounds__(512) void gramsim3_kernel(
    const unsigned short* __restrict__ hiT, const unsigned short* __restrict__ loT,
    const unsigned short* __restrict__ aud_bf,
    float* __restrict__ G, float* __restrict__ sumWA, float* __restrict__ sumW)
{
  const int bid = blockIdx.x;
  const int slot = bid & 7, seq = bid >> 3;
  const int b = slot + 8*(seq>>1), h = seq & 1;   // pair 8 slots apart -> same XCD
  const int tid = threadIdx.x, lane = tid & 63, w = tid >> 6;
  // gram roles
  const int cbase = 7*h, ncl = 7 - h;             // col tiles: 0..6 / 7..12
  const int nr = (w<5)?2:1;                       // row tiles: {w, w+8}
  // sim roles
  const int wr = w >> 2, wc = w & 3;              // 2 p-groups x 4 n-groups
  const int pbase = (wr==0)?0:7, npt = 7-wr;      // 7 / 6 p-tiles
  const unsigned short* hb = hiT + (size_t)b*8*PR*64;
  const unsigned short* lb = loT + (size_t)b*8*PR*64;
  float* Gb = G + (size_t)b*NP*NP;
  __shared__ short smh[PROWS*LSTR];               // 29.95 KB
  __shared__ short sml[PROWS*LSTR];               // 29.95 KB
  __shared__ short sma[128*LSTR];                 // 18.4 KB
  __shared__ float sred[2][2][4][2][16];          // 2 KB   (total ~80.4 KB -> 2 blocks/CU)

  f32x4 gacc[2][7];
  #pragma unroll
  for (int i=0;i<2;++i)
    #pragma unroll
    for (int j=0;j<7;++j) gacc[i][j]=(f32x4){0,0,0,0};
  f32x4 sacc[7][2];
  #pragma unroll
  for (int i=0;i<7;++i)
    #pragma unroll
    for (int n=0;n<2;++n) sacc[i][n]=(f32x4){0,0,0,0};

  for (int sl=0; sl<8; ++sl){
    __syncthreads();
    for (int j=tid; j<PROWS*8; j+=512){
      int p = j>>3, o = j&7;
      size_t src = ((size_t)sl*PR + p)*64 + o*8;   // p>=196 overruns harmlessly (discarded rows)
      *(uint4*)&smh[p*LSTR + o*8] = *(const uint4*)(hb + src);
      *(uint4*)&sml[p*LSTR + o*8] = *(const uint4*)(lb + src);
    }
    for (int j=tid; j<128*8; j+=512){
      int n = j>>3, o = j&7;
      *(uint4*)&sma[n*LSTR + o*8] = *(const uint4*)(aud_bf + (size_t)(h*128+n)*NC + sl*64 + o*8);
    }
    __syncthreads();
    #pragma unroll
    for (int kk=0; kk<2; ++kk){
      // ---- gram MFMAs (exact gram2 order) ----
      {
        bf16x8 Ah[2], Al[2];
        #pragma unroll
        for (int i=0;i<2;++i){
          if (i<nr){
            int r = (w + 8*i)*16 + (lane&15);
            Ah[i] = *(const bf16x8*)&smh[r*LSTR + kk*32 + (lane>>4)*8];
            Al[i] = *(const bf16x8*)&sml[r*LSTR + kk*32 + (lane>>4)*8];
          }
        }
        #pragma unroll
        for (int j=0;j<7;++j){
          if (j<ncl){
            int r = (cbase+j)*16 + (lane&15);
            bf16x8 Bh = *(const bf16x8*)&smh[r*LSTR + kk*32 + (lane>>4)*8];
            bf16x8 Bl = *(const bf16x8*)&sml[r*LSTR + kk*32 + (lane>>4)*8];
            #pragma unroll
            for (int i=0;i<2;++i){
              if (i<nr){
                gacc[i][j] = __builtin_amdgcn_mfma_f32_16x16x32_bf16(Ah[i], Bh, gacc[i][j], 0,0,0);
                gacc[i][j] = __builtin_amdgcn_mfma_f32_16x16x32_bf16(Ah[i], Bl, gacc[i][j], 0,0,0);
                gacc[i][j] = __builtin_amdgcn_mfma_f32_16x16x32_bf16(Al[i], Bh, gacc[i][j], 0,0,0);
              }
            }
          }
        }
      }
      // ---- sim MFMAs (exact simgemm2 order) ----
      {
        bf16x8 Ah[7];
        #pragma unroll
        for (int i=0;i<7;++i){
          if (i<npt){
            int r = (pbase+i)*16 + (lane&15);
            Ah[i] = *(const bf16x8*)&smh[r*LSTR + kk*32 + (lane>>4)*8];
          }
        }
        #pragma unroll
        for (int n=0;n<2;++n){
          int r = (wc*2+n)*16 + (lane&15);
          bf16x8 Bn = *(const bf16x8*)&sma[r*LSTR + kk*32 + (lane>>4)*8];
          #pragma unroll
          for (int i=0;i<7;++i)
            if (i<npt)
              sacc[i][n] = __builtin_amdgcn_mfma_f32_16x16x32_bf16(Ah[i], Bn, sacc[i][n], 0,0,0);
        }
      }
    }
  }

  // ---- gram epilogue ----
  {
    const int r0 = (lane>>4)*4, colL = lane & 15;
    #pragma unroll
    for (int i=0;i<2;++i){
      #pragma unroll
      for (int j=0;j<7;++j){
        if (i<nr && j<ncl){
          int row = (w+8*i)*16 + r0;
          int col = (cbase+j)*16 + colL;
          if (col < NP){
            #pragma unroll
            for (int jj=0;jj<4;++jj){
              if (row+jj < NP) Gb[(size_t)(row+jj)*NP + col] = gacc[i][j][jj];
            }
          }
        }
      }
    }
  }

  // ---- sim epilogue (exact simgemm2) ----
  float swa[2]={0,0}, sw[2]={0,0};
  #pragma unroll
  for (int n=0;n<2;++n){
    #pragma unroll
    for (int i=0;i<7;++i){
      if (i<npt){
        int rowbase = (pbase+i)*16 + (lane>>4)*4;
        #pragma unroll
        for (int jj=0;jj<4;++jj){
          if (rowbase+jj < NP){
            float v = sacc[i][n][jj];
            float wgt = sigf((v-0.65f)/0.03f);
            swa[n] += wgt*v; sw[n] += wgt;
          }
        }
      }
    }
  }
  #pragma unroll
  for (int n=0;n<2;++n){
    swa[n] += __shfl_xor(swa[n],16); swa[n] += __shfl_xor(swa[n],32);
    sw[n]  += __shfl_xor(sw[n],16);  sw[n]  += __shfl_xor(sw[n],32);
  }
  if (lane < 16){
    #pragma unroll
    for (int n=0;n<2;++n){
      sred[0][wr][wc][n][lane] = swa[n];
      sred[1][wr][wc][n][lane] = sw[n];
    }
  }
  __syncthreads();
  if (tid < 128){
    int wc2 = tid>>5, n2 = (tid>>4)&1, col = tid&15;
    float a = sred[0][0][wc2][n2][col] + sred[0][1][wc2][n2][col];
    float s = sred[1][0][wc2][n2][col] + sred[1][1][wc2][n2][col];
    int kcol = h*128 + (wc2*2+n2)*16 + col;
    sumWA[(size_t)b*NB + kcol] = a;
    sumW [(size_t)b*NB + kcol] = s;
  }
}

// ---------------- selection loop: pl/cs reduction + G-in-LDS decisions + obj writes ----------------
__global__ __launch_bounds__(1024) void loop6_kernel(
    const double* __restrict__ ppl, const double* __restrict__ pcs,
    const float* __restrict__ G,
    const unsigned short* __restrict__ hiT, const unsigned short* __restrict__ loT,
    float* __restrict__ pl, float* __restrict__ out_pl,
    float* __restrict__ obj)
{
  const int b = blockIdx.x, tid = threadIdx.x, lane = tid & 63, w = tid >> 6;
  const float* Gb = G + (size_t)b*NP*NP;
  __shared__ float sG[NP*NP];                 // 153,664 B
  __shared__ float s_pl[NP], s_wl[NP], s_csL[NP], s_gd[NP];
  __shared__ double gwd[NP];
  __shared__ double s_wred[16];
  __shared__ double s_bc;
  __shared__ int s_q[NIT]; __shared__ int s_z[NIT];

  #pragma unroll
  for (int k=0;k<10;++k){
    int j = k*1024 + tid;
    if (j < NP*NP/4) ((float4*)sG)[j] = ((const float4*)Gb)[j];
  }
  float negw_t = 0.f;
  if (tid < NP){
    double a=0.0, s=0.0;
    #pragma unroll
    for (int part=0; part<8; ++part){
      a += ppl[(size_t)(b*8+part)*NP + tid];
      s += pcs[(size_t)(b*8+part)*NP + tid];
    }
    float plv=(float)a;
    float csv=(float)s;
    pl[b*NP+tid]=plv; out_pl[b*NP+tid]=plv;
    s_pl[tid] = plv;
    s_csL[tid] = plv*csv;
    negw_t = 1.0f - sigf((plv-0.40f)/0.03f);
    s_wl[tid] = plv*negw_t;
    s_gd[tid] = Gb[(size_t)tid*NP + tid];
  }
  __syncthreads();

  {
    int p = tid >> 2, qg = tid & 3;
    double a = 0.0;
    if (p < NP){
      for (int q=qg*49; q<qg*49+49; ++q) a += (double)sG[q*NP + p] * (double)s_wl[q];
    }
    a += dshfl_xor(a,1); a += dshfl_xor(a,2);
    if (qg==0 && p<NP) gwd[p] = a;
  }
  __syncthreads();

  double r = (tid<NP) ? (double)s_wl[tid]*gwd[tid] : 0.0;
  #pragma unroll
  for (int m=1;m<64;m<<=1) r += dshfl_xor(r,m);
  if (lane==0) s_wred[w] = r;
  __syncthreads();
  if (tid==0){ double t=0.0; for (int i=0;i<16;++i) t += s_wred[i]; s_bc = t; }
  __syncthreads();
  const double S2 = s_bc;
  __syncthreads();

  r = (tid<NP) ? (double)negw_t*(double)s_csL[tid] : 0.0;
  #pragma unroll
  for (int m=1;m<64;m<<=1) r += dshfl_xor(r,m);
  if (lane==0) s_wred[w] = r;
  __syncthreads();
  if (tid==0){ double t=0.0; for (int i=0;i<16;++i) t += s_wred[i]; s_bc = t; }
  __syncthreads();
  const double Swl = s_bc;
  __syncthreads();

  if (tid < NP){
    const double e = (double)1e-6f;
    double pld = (double)s_pl[tid];
    double d0sq = pld*pld*(double)s_gd[tid]
                - (2.0/196.0)*pld*gwd[tid]
                + S2/(196.0*196.0)
                + 2.0*e*((double)s_csL[tid] - Swl/196.0)
                + 512.0*e*e;
    if (d0sq < 0.0) d0sq = 0.0;
    gwd[tid] = d0sq;
  }
  __syncthreads();

  if (w == 0){
    float plv[4], csL[4], gdd[4], posv[4];
    double d0sq[4];
    bool alr[4];
    #pragma unroll
    for (int s=0;s<4;++s){
      int p = lane + 64*s;
      bool valid = p < NP;
      plv[s]  = valid ? s_pl[p]  : 0.f;
      csL[s]  = valid ? s_csL[p] : 0.f;
      gdd[s]  = valid ? s_gd[p]  : 0.f;
      d0sq[s] = valid ? gwd[p]   : 0.0;
      posv[s] = valid ? plv[s]   : -INFINITY;
      alr[s] = false;
    }
    bool endp = false;

    for (int t=0;t<NIT;++t){
      float v = posv[0]; int ix = lane;
      #pragma unroll
      for (int s=1;s<4;++s){
        if (posv[s] > v){ v = posv[s]; ix = lane + 64*s; }
      }
      #pragma unroll
      for (int m=1;m<64;m<<=1){
        float vv = __shfl_xor(v, m);
        int   ii = __shfl_xor(ix, m);
        if (vv>v || (vv==v && ii<ix)){ v=vv; ix=ii; }
      }
      const int q = ix;
      const float plq  = s_pl[q];
      const float gqq  = s_gd[q];
      const float csLq = s_csL[q];
      if (lane==0){ s_q[t] = q; s_z[t] = endp ? 1 : 0; }

      int cnt = 0;
      #pragma unroll
      for (int s=0;s<4;++s){
        int p = lane + 64*s;
        if (p<NP && !alr[s]){
          float Gpq = sG[q*NP + p];
          double plp=(double)plv[s], dq=(double)plq;
          const double e=(double)1e-6f;
          double d2 = plp*plp*(double)gdd[s]
                    - 2.0*plp*dq*(double)Gpq
                    + dq*dq*(double)gqq
                    + 2.0*e*((double)csL[s]-(double)csLq)
                    + 512.0*e*e;
          if (d2<0.0) d2=0.0;
          if (d2 < d0sq[s]){ alr[s]=true; posv[s]=posv[s]*0.0f; cnt++; }
        }
      }
      float mx = fmaxf(fmaxf(posv[0],posv[1]),fmaxf(posv[2],posv[3]));
      #pragma unroll
      for (int m=1;m<64;m<<=1){
        cnt += __shfl_xor(cnt, m);
        mx = fmaxf(mx, __shfl_xor(mx, m));
      }
      if (cnt==0 || mx<0.1f) endp=true;
    }
  }
  __syncthreads();

  for (int j=tid; j<NIT*64; j+=1024){
    int t = j >> 6, l8 = j & 63;
    int part = l8 >> 3, off = l8 & 7;
    float o8[8];
    if (s_z[t]){
      #pragma unroll
      for (int e=0;e<8;++e) o8[e]=0.f;
    } else {
      int q = s_q[t];
      float plq = s_pl[q];
      size_t src = ((size_t)(b*8+part)*PR + q)*64 + off*8;
      uint4 hv = *(const uint4*)(hiT + src);
      uint4 lv = *(const uint4*)(loT + src);
      const unsigned* hw = (const unsigned*)&hv;
      const unsigned* lw = (const unsigned*)&lv;
      #pragma unroll
      for (int k2=0;k2<4;++k2){
        float x0 = bf2f((unsigned short)(hw[k2]&0xffff)) + bf2f((unsigned short)(lw[k2]&0xffff));
        float x1 = bf2f((unsigned short)(hw[k2]>>16))    + bf2f((unsigned short)(lw[k2]>>16));
        o8[2*k2]   = x0*plq;
        o8[2*k2+1] = x1*plq;
      }
    }
    float* op = obj + ((size_t)t*NB + b)*NC + l8*8;
    *(float4*)&op[0] = *(float4*)&o8[0];
    *(float4*)&op[4] = *(float4*)&o8[4];
  }
}

// ---------------- loss: per-b block (sims inline), then sum ----------------
__global__ __launch_bounds__(256) void finalize_b2(
    const float* __restrict__ pl,
    const float* __restrict__ sumWA, const float* __restrict__ sumW,
    float* __restrict__ lossb)
{
  const int b = blockIdx.x, k = threadIdx.x;
  __shared__ float s_red[256];
  __shared__ double s_redd[256];

  float plv = (k<NP)? pl[b*NP+k] : 0.f;
  float pmw = (k<NP)? sigf((plv-0.65f)/0.03f) : 0.f;
  float negw= (k<NP)? 1.0f - sigf((plv-0.40f)/0.03f) : 0.f;
  double rr[4];
  rr[0]=(k<NP)?(double)pmw*(double)plv:0.0;
  rr[1]=(k<NP)?(double)pmw:0.0;
  rr[2]=(k<NP)?(double)negw*(double)plv:0.0;
  rr[3]=(k<NP)?(double)negw:0.0;
  double res[4];
  for (int i=0;i<4;++i){
    __syncthreads();
    s_redd[k]=rr[i];
    __syncthreads();
    for (int s=128;s>0;s>>=1){ if (k<s) s_redd[k]+=s_redd[k+s]; __syncthreads(); }
    res[i]=s_redd[0];
  }
  const float sim1v = (float)(res[0]/res[1]);
  const float sim2v = (float)(res[2]/res[3]);
  __syncthreads();

  const float T = 0.07f;
  float s = sumWA[(size_t)b*NB+k]/sumW[(size_t)b*NB+k];
  if (k==b) s *= -99.0f;
  const float lk = s/T;
  const float l0 = sim1v/T, ll = sim2v/T;
  s_red[k]=lk; __syncthreads();
  for (int st=128;st>0;st>>=1){ if(k<st) s_red[k]=fmaxf(s_red[k],s_red[k+st]); __syncthreads(); }
  const float m = fmaxf(s_red[0], fmaxf(l0,ll));
  __syncthreads();
  double e = (double)expf(lk-m);
  if (k==0) e += (double)expf(l0-m)+(double)expf(ll-m);
  s_redd[k]=e; __syncthreads();
  for (int st=128;st>0;st>>=1){ if(k<st) s_redd[k]+=s_redd[k+st]; __syncthreads(); }
  if (k==0) lossb[b] = -(float)((double)(l0-m) - log(s_redd[0]));
}

__global__ __launch_bounds__(256) void finalize_sum(const float* __restrict__ lossb, float* __restrict__ out_loss)
{
  const int tid = threadIdx.x;
  __shared__ double sr[256];
  sr[tid]=(double)lossb[tid]; __syncthreads();
  for (int st=128;st>0;st>>=1){ if(tid<st) sr[tid]+=sr[tid+st]; __syncthreads(); }
  if (tid==0) out_loss[0]=(float)(sr[0]/256.0);
}

extern "C" void kernel_launch(void* const* d_in, const int* in_sizes, int n_in,
                              void* d_out, int out_size, void* d_ws, size_t ws_size,
                              hipStream_t stream)
{
  const float* img = (const float*)d_in[0];
  const float* aud = (const float*)d_in[1];
  float* out = (float*)d_out;
  float* ws  = (float*)d_ws;

  // ws layout (~142 MB < 149.6 MB proven by R4-R17 runs)
  float* pl    = ws;                                           // 50176 f
  unsigned short* aud_bf = (unsigned short*)(pl + NB*NP);      // 131072 us
  unsigned short* hiT = aud_bf + NB*NC;                        // 256*8*196*64 us (49.0 MB)
  unsigned short* loT = hiT + (size_t)NB*8*PR*64;              // 49.0 MB
  float* G     = (float*)(loT + (size_t)NB*8*PR*64);           // 9,834,496 f (37.5 MB)
  double* ppl  = (double*)(G + (size_t)NB*NP*NP);              // NB*8*196 doubles (3.2 MB)
  double* pcs  = ppl + (size_t)NB*8*NP;                        // 3.2 MB
  float* lossb = (float*)(pcs + (size_t)NB*8*NP);              // 256 f

  // sumWA/sumW placed after lossb (ppl/pcs stay live until loop6)
  float* sumWA = lossb + NB;
  float* sumW  = sumWA + NB*NB;

  float* out_loss = out;
  float* out_pl   = out + 1;
  float* out_obj  = out + 1 + NB*NP;

  hipLaunchKernelGGL(convert4_kernel, dim3(NB*8),  dim3(512),  0, stream, img, aud, hiT, loT, aud_bf, ppl, pcs);
  hipLaunchKernelGGL(gramsim3_kernel, dim3(NB*2),  dim3(512),  0, stream, hiT, loT, aud_bf, G, sumWA, sumW);
  hipLaunchKernelGGL(loop6_kernel,    dim3(NB),    dim3(1024), 0, stream, ppl, pcs, G, hiT, loT, pl, out_pl, out_obj);
  hipLaunchKernelGGL(finalize_b2,     dim3(NB),    dim3(256),  0, stream, pl, sumWA, sumW, lossb);
  hipLaunchKernelGGL(finalize_sum,    dim3(1),     dim3(256),  0, stream, lossb, out_loss);
}

// Round 19
// 187.668 us; speedup vs baseline: 1.1187x; 1.1187x over previous
//
#include <hip/hip_runtime.h>
#include <hip/hip_bf16.h>
#include <math.h>

#define NB 256
#define NC 512
#define NP 196
#define NIT 32
#define PROWS 208          // LDS row count (13 tiles of 16); global panels store 196 rows/part
#define PR 196             // global panel rows per part
#define LSTR 72            // LDS short-row stride for 64-c slices
#define SFSTR 211

typedef __attribute__((ext_vector_type(8))) short bf16x8;
typedef __attribute__((ext_vector_type(4))) float f32x4;

__device__ __forceinline__ float sigf(float z){ return 1.0f/(1.0f+expf(-z)); }

__device__ __forceinline__ unsigned short f2bf(float x){
  return __bfloat16_as_ushort(__float2bfloat16(x));
}
__device__ __forceinline__ float bf2f(unsigned short h){
  union{float f; unsigned u;} v; v.u = ((unsigned)h)<<16; return v.f;
}
__device__ __forceinline__ double dshfl_xor(double v, int m){
  int lo = __shfl_xor(__double2loint(v), m);
  int hi = __shfl_xor(__double2hiint(v), m);
  return __hiloint2double(hi, lo);
}

// panel layout: hiT/loT [b][part8][PR][64]  (row-part = 128B contiguous)

// ---------------- transpose+convert+partial-pl (+ aud->bf16 on part==0) ----------------
__global__ __launch_bounds__(512) void convert4_kernel(
    const float* __restrict__ img, const float* __restrict__ aud,
    unsigned short* __restrict__ hiT, unsigned short* __restrict__ loT,
    unsigned short* __restrict__ aud_bf,
    double* __restrict__ ppl, double* __restrict__ pcs)   // [NB][8][196]
{
  const int bid = blockIdx.x;
  const int b = bid & 255, part = bid >> 8;     // parts of b share XCD (256%8==0)
  const int tid = threadIdx.x;
  const float* imgb = img + (size_t)b*NC*NP + (size_t)part*64*NP;
  __shared__ float sf[64*SFSTR];                // 54.0 KB
  __shared__ float s_aud[64];
  if (part == 0) aud_bf[b*NC + tid] = f2bf(aud[b*NC + tid]);   // 512 threads = NC
  if (tid < 64) s_aud[tid] = aud[b*NC + part*64 + tid];

  for (int j=tid; j<64*49; j+=512){
    int p4 = j % 49, c = j / 49;
    float4 v = *(const float4*)&imgb[(size_t)c*NP + p4*4];
    sf[c*SFSTR + p4*4+0]=v.x; sf[c*SFSTR + p4*4+1]=v.y;
    sf[c*SFSTR + p4*4+2]=v.z; sf[c*SFSTR + p4*4+3]=v.w;
  }
  __syncthreads();

  unsigned short* hp = hiT + (size_t)(b*8+part)*PR*64;
  unsigned short* lp = loT + (size_t)(b*8+part)*PR*64;
  for (int j=tid; j<PROWS*8; j+=512){
    int p = j>>3, o = j&7;
    unsigned hw[4], lw[4];
    double dot=0.0, sm=0.0;
    #pragma unroll
    for (int k2=0;k2<4;++k2){
      int c = o*8 + 2*k2;
      float x0 = (p<NP) ? sf[c*SFSTR + p]     : 0.f;
      float x1 = (p<NP) ? sf[(c+1)*SFSTR + p] : 0.f;
      unsigned short h0=f2bf(x0), h1=f2bf(x1);
      unsigned short l0=f2bf(x0-bf2f(h0)), l1=f2bf(x1-bf2f(h1));
      hw[k2] = (unsigned)h0 | ((unsigned)h1<<16);
      lw[k2] = (unsigned)l0 | ((unsigned)l1<<16);
      dot += (double)x0*(double)s_aud[c] + (double)x1*(double)s_aud[c+1];
      sm  += (double)x0 + (double)x1;
    }
    if (p < NP){   // only 196 real rows stored
      *(uint4*)&hp[p*64 + o*8] = *(uint4*)hw;
      *(uint4*)&lp[p*64 + o*8] = *(uint4*)lw;
    }
    dot += dshfl_xor(dot,1); dot += dshfl_xor(dot,2); dot += dshfl_xor(dot,4);
    sm  += dshfl_xor(sm,1);  sm  += dshfl_xor(sm,2);  sm  += dshfl_xor(sm,4);
    if (o==0 && p<NP){
      ppl[(size_t)(b*8+part)*NP + p] = dot;
      pcs[(size_t)(b*8+part)*NP + p] = sm;
    }
  }
}

// ---------------- Gram (split-bf16), 2 blocks per b, pair-adjacent same-XCD ----------------
__global__ __launch_bounds__(512) void gram2_kernel(
    const unsigned short* __restrict__ hiT, const unsigned short* __restrict__ loT,
    float* __restrict__ G)
{
  const int bid = blockIdx.x;
  const int slot = bid & 7, seq = bid >> 3;
  const int b = slot + 8*(seq>>1), h = seq & 1;   // pair 8 slots apart -> same XCD
  const int cbase = 7*h, ncl = 7 - h;             // col tiles: 0..6 / 7..12
  const int tid = threadIdx.x, lane = tid & 63, w = tid >> 6;
  const int nr = (w<5)?2:1;                       // row tiles: {w, w+8}
  const unsigned short* hb = hiT + (size_t)b*8*PR*64;
  const unsigned short* lb = loT + (size_t)b*8*PR*64;
  float* Gb = G + (size_t)b*NP*NP;
  __shared__ short smh[PROWS*LSTR];
  __shared__ short sml[PROWS*LSTR];

  f32x4 acc[2][7];
  #pragma unroll
  for (int i=0;i<2;++i)
    #pragma unroll
    for (int j=0;j<7;++j) acc[i][j]=(f32x4){0,0,0,0};

  for (int sl=0; sl<8; ++sl){
    __syncthreads();
    for (int j=tid; j<PROWS*8; j+=512){
      int p = j>>3, o = j&7;
      size_t src = ((size_t)sl*PR + p)*64 + o*8;   // p>=196 overruns harmlessly (discarded rows)
      *(uint4*)&smh[p*LSTR + o*8] = *(const uint4*)(hb + src);
      *(uint4*)&sml[p*LSTR + o*8] = *(const uint4*)(lb + src);
    }
    __syncthreads();
    #pragma unroll
    for (int kk=0; kk<2; ++kk){
      bf16x8 Ah[2], Al[2];
      #pragma unroll
      for (int i=0;i<2;++i){
        if (i<nr){
          int r = (w + 8*i)*16 + (lane&15);
          Ah[i] = *(const bf16x8*)&smh[r*LSTR + kk*32 + (lane>>4)*8];
          Al[i] = *(const bf16x8*)&sml[r*LSTR + kk*32 + (lane>>4)*8];
        }
      }
      #pragma unroll
      for (int j=0;j<7;++j){
        if (j<ncl){
          int r = (cbase+j)*16 + (lane&15);
          bf16x8 Bh = *(const bf16x8*)&smh[r*LSTR + kk*32 + (lane>>4)*8];
          bf16x8 Bl = *(const bf16x8*)&sml[r*LSTR + kk*32 + (lane>>4)*8];
          #pragma unroll
          for (int i=0;i<2;++i){
            if (i<nr){
              acc[i][j] = __builtin_amdgcn_mfma_f32_16x16x32_bf16(Ah[i], Bh, acc[i][j], 0,0,0);
              acc[i][j] = __builtin_amdgcn_mfma_f32_16x16x32_bf16(Ah[i], Bl, acc[i][j], 0,0,0);
              acc[i][j] = __builtin_amdgcn_mfma_f32_16x16x32_bf16(Al[i], Bh, acc[i][j], 0,0,0);
            }
          }
        }
      }
    }
  }

  const int r0 = (lane>>4)*4, colL = lane & 15;
  #pragma unroll
  for (int i=0;i<2;++i){
    #pragma unroll
    for (int j=0;j<7;++j){
      if (i<nr && j<ncl){
        int row = (w+8*i)*16 + r0;
        int col = (cbase+j)*16 + colL;
        if (col < NP){
          #pragma unroll
          for (int jj=0;jj<4;++jj){
            if (row+jj < NP) Gb[(size_t)(row+jj)*NP + col] = acc[i][j][jj];
          }
        }
      }
    }
  }
}

// ---------------- selection loop: pl/cs reduction + G-in-LDS decisions + obj writes ----------------
__global__ __launch_bounds__(1024) void loop6_kernel(
    const double* __restrict__ ppl, const double* __restrict__ pcs,
    const float* __restrict__ G,
    const unsigned short* __restrict__ hiT, const unsigned short* __restrict__ loT,
    float* __restrict__ pl, float* __restrict__ out_pl,
    float* __restrict__ obj)
{
  const int b = blockIdx.x, tid = threadIdx.x, lane = tid & 63, w = tid >> 6;
  const float* Gb = G + (size_t)b*NP*NP;
  __shared__ float sG[NP*NP];                 // 153,664 B
  __shared__ float s_pl[NP], s_wl[NP], s_csL[NP], s_gd[NP];
  __shared__ double gwd[NP];
  __shared__ double s_wred[16];
  __shared__ double s_bc;
  __shared__ int s_q[NIT]; __shared__ int s_z[NIT];

  // stage G
  #pragma unroll
  for (int k=0;k<10;++k){
    int j = k*1024 + tid;
    if (j < NP*NP/4) ((float4*)sG)[j] = ((const float4*)Gb)[j];
  }
  // pl/cs from partials (prep3's exact reduction)
  float negw_t = 0.f;
  if (tid < NP){
    double a=0.0, s=0.0;
    #pragma unroll
    for (int part=0; part<8; ++part){
      a += ppl[(size_t)(b*8+part)*NP + tid];
      s += pcs[(size_t)(b*8+part)*NP + tid];
    }
    float plv=(float)a;
    float csv=(float)s;
    pl[b*NP+tid]=plv; out_pl[b*NP+tid]=plv;
    s_pl[tid] = plv;
    s_csL[tid] = plv*csv;
    negw_t = 1.0f - sigf((plv-0.40f)/0.03f);
    s_wl[tid] = plv*negw_t;
    s_gd[tid] = Gb[(size_t)tid*NP + tid];
  }
  __syncthreads();

  // gw_p = sum_q G[q][p]*wl[q], 4 threads per p
  {
    int p = tid >> 2, qg = tid & 3;
    double a = 0.0;
    if (p < NP){
      for (int q=qg*49; q<qg*49+49; ++q) a += (double)sG[q*NP + p] * (double)s_wl[q];
    }
    a += dshfl_xor(a,1); a += dshfl_xor(a,2);
    if (qg==0 && p<NP) gwd[p] = a;
  }
  __syncthreads();

  double r = (tid<NP) ? (double)s_wl[tid]*gwd[tid] : 0.0;
  #pragma unroll
  for (int m=1;m<64;m<<=1) r += dshfl_xor(r,m);
  if (lane==0) s_wred[w] = r;
  __syncthreads();
  if (tid==0){ double t=0.0; for (int i=0;i<16;++i) t += s_wred[i]; s_bc = t; }
  __syncthreads();
  const double S2 = s_bc;
  __syncthreads();

  r = (tid<NP) ? (double)negw_t*(double)s_csL[tid] : 0.0;
  #pragma unroll
  for (int m=1;m<64;m<<=1) r += dshfl_xor(r,m);
  if (lane==0) s_wred[w] = r;
  __syncthreads();
  if (tid==0){ double t=0.0; for (int i=0;i<16;++i) t += s_wred[i]; s_bc = t; }
  __syncthreads();
  const double Swl = s_bc;
  __syncthreads();

  if (tid < NP){
    const double e = (double)1e-6f;
    double pld = (double)s_pl[tid];
    double d0sq = pld*pld*(double)s_gd[tid]
                - (2.0/196.0)*pld*gwd[tid]
                + S2/(196.0*196.0)
                + 2.0*e*((double)s_csL[tid] - Swl/196.0)
                + 512.0*e*e;
    if (d0sq < 0.0) d0sq = 0.0;
    gwd[tid] = d0sq;
  }
  __syncthreads();

  // serial decisions: wave 0 only
  if (w == 0){
    float plv[4], csL[4], gdd[4], posv[4];
    double d0sq[4];
    bool alr[4];
    #pragma unroll
    for (int s=0;s<4;++s){
      int p = lane + 64*s;
      bool valid = p < NP;
      plv[s]  = valid ? s_pl[p]  : 0.f;
      csL[s]  = valid ? s_csL[p] : 0.f;
      gdd[s]  = valid ? s_gd[p]  : 0.f;
      d0sq[s] = valid ? gwd[p]   : 0.0;
      posv[s] = valid ? plv[s]   : -INFINITY;
      alr[s] = false;
    }
    bool endp = false;

    for (int t=0;t<NIT;++t){
      float v = posv[0]; int ix = lane;
      #pragma unroll
      for (int s=1;s<4;++s){
        if (posv[s] > v){ v = posv[s]; ix = lane + 64*s; }
      }
      #pragma unroll
      for (int m=1;m<64;m<<=1){
        float vv = __shfl_xor(v, m);
        int   ii = __shfl_xor(ix, m);
        if (vv>v || (vv==v && ii<ix)){ v=vv; ix=ii; }
      }
      const int q = ix;
      const float plq  = s_pl[q];
      const float gqq  = s_gd[q];
      const float csLq = s_csL[q];
      if (lane==0){ s_q[t] = q; s_z[t] = endp ? 1 : 0; }

      int cnt = 0;
      #pragma unroll
      for (int s=0;s<4;++s){
        int p = lane + 64*s;
        if (p<NP && !alr[s]){
          float Gpq = sG[q*NP + p];
          double plp=(double)plv[s], dq=(double)plq;
          const double e=(double)1e-6f;
          double d2 = plp*plp*(double)gdd[s]
                    - 2.0*plp*dq*(double)Gpq
                    + dq*dq*(double)gqq
                    + 2.0*e*((double)csL[s]-(double)csLq)
                    + 512.0*e*e;
          if (d2<0.0) d2=0.0;
          if (d2 < d0sq[s]){ alr[s]=true; posv[s]=posv[s]*0.0f; cnt++; }
        }
      }
      float mx = fmaxf(fmaxf(posv[0],posv[1]),fmaxf(posv[2],posv[3]));
      #pragma unroll
      for (int m=1;m<64;m<<=1){
        cnt += __shfl_xor(cnt, m);
        mx = fmaxf(mx, __shfl_xor(mx, m));
      }
      if (cnt==0 || mx<0.1f) endp=true;
    }
  }
  __syncthreads();

  // obj writes (all 16 waves)
  for (int j=tid; j<NIT*64; j+=1024){
    int t = j >> 6, l8 = j & 63;
    int part = l8 >> 3, off = l8 & 7;
    float o8[8];
    if (s_z[t]){
      #pragma unroll
      for (int e=0;e<8;++e) o8[e]=0.f;
    } else {
      int q = s_q[t];
      float plq = s_pl[q];
      size_t src = ((size_t)(b*8+part)*PR + q)*64 + off*8;
      uint4 hv = *(const uint4*)(hiT + src);
      uint4 lv = *(const uint4*)(loT + src);
      const unsigned* hw = (const unsigned*)&hv;
      const unsigned* lw = (const unsigned*)&lv;
      #pragma unroll
      for (int k2=0;k2<4;++k2){
        float x0 = bf2f((unsigned short)(hw[k2]&0xffff)) + bf2f((unsigned short)(lw[k2]&0xffff));
        float x1 = bf2f((unsigned short)(hw[k2]>>16))    + bf2f((unsigned short)(lw[k2]>>16));
        o8[2*k2]   = x0*plq;
        o8[2*k2+1] = x1*plq;
      }
    }
    float* op = obj + ((size_t)t*NB + b)*NC + l8*8;
    *(float4*)&op[0] = *(float4*)&o8[0];
    *(float4*)&op[4] = *(float4*)&o8[4];
  }
}

// ---------------- all_logits GEMM + fused sigmoid sums, pair-adjacent same-XCD ----------------
__global__ __launch_bounds__(512) void simgemm2_kernel(
    const unsigned short* __restrict__ hiT, const unsigned short* __restrict__ aud_bf,
    float* __restrict__ sumWA, float* __restrict__ sumW)
{
  const int bid = blockIdx.x;
  const int slot = bid & 7, seq = bid >> 3;
  const int b = slot + 8*(seq>>1), h = seq & 1;   // h: n-half (128 audio cols)
  const int tid = threadIdx.x, lane = tid & 63, w = tid >> 6;
  const int wr = w >> 2, wc = w & 3;              // 2 p-groups x 4 n-groups
  const int pbase = (wr==0)?0:7, npt = 7-wr;      // 7 / 6 p-tiles
  const unsigned short* hb = hiT + (size_t)b*8*PR*64;
  __shared__ short smh[PROWS*LSTR];
  __shared__ short sma[128*LSTR];
  __shared__ float sred[2][2][4][2][16];

  f32x4 acc[7][2];
  #pragma unroll
  for (int i=0;i<7;++i)
    #pragma unroll
    for (int n=0;n<2;++n) acc[i][n]=(f32x4){0,0,0,0};

  for (int sl=0; sl<8; ++sl){
    __syncthreads();
    for (int j=tid; j<PROWS*8; j+=512){
      int p = j>>3, o = j&7;
      *(uint4*)&smh[p*LSTR + o*8] = *(const uint4*)(hb + ((size_t)sl*PR + p)*64 + o*8);
    }
    for (int j=tid; j<128*8; j+=512){
      int n = j>>3, o = j&7;
      *(uint4*)&sma[n*LSTR + o*8] = *(const uint4*)(aud_bf + (size_t)(h*128+n)*NC + sl*64 + o*8);
    }
    __syncthreads();
    #pragma unroll
    for (int kk=0; kk<2; ++kk){
      bf16x8 Ah[7];
      #pragma unroll
      for (int i=0;i<7;++i){
        if (i<npt){
          int r = (pbase+i)*16 + (lane&15);
          Ah[i] = *(const bf16x8*)&smh[r*LSTR + kk*32 + (lane>>4)*8];
        }
      }
      #pragma unroll
      for (int n=0;n<2;++n){
        int r = (wc*2+n)*16 + (lane&15);
        bf16x8 Bn = *(const bf16x8*)&sma[r*LSTR + kk*32 + (lane>>4)*8];
        #pragma unroll
        for (int i=0;i<7;++i)
          if (i<npt)
            acc[i][n] = __builtin_amdgcn_mfma_f32_16x16x32_bf16(Ah[i], Bn, acc[i][n], 0,0,0);
      }
    }
  }

  float swa[2]={0,0}, sw[2]={0,0};
  #pragma unroll
  for (int n=0;n<2;++n){
    #pragma unroll
    for (int i=0;i<7;++i){
      if (i<npt){
        int rowbase = (pbase+i)*16 + (lane>>4)*4;
        #pragma unroll
        for (int jj=0;jj<4;++jj){
          if (rowbase+jj < NP){
            float v = acc[i][n][jj];
            float wgt = sigf((v-0.65f)/0.03f);
            swa[n] += wgt*v; sw[n] += wgt;
          }
        }
      }
    }
  }
  #pragma unroll
  for (int n=0;n<2;++n){
    swa[n] += __shfl_xor(swa[n],16); swa[n] += __shfl_xor(swa[n],32);
    sw[n]  += __shfl_xor(sw[n],16);  sw[n]  += __shfl_xor(sw[n],32);
  }
  if (lane < 16){
    #pragma unroll
    for (int n=0;n<2;++n){
      sred[0][wr][wc][n][lane] = swa[n];
      sred[1][wr][wc][n][lane] = sw[n];
    }
  }
  __syncthreads();
  if (tid < 128){
    int wc2 = tid>>5, n2 = (tid>>4)&1, col = tid&15;
    float a = sred[0][0][wc2][n2][col] + sred[0][1][wc2][n2][col];
    float s = sred[1][0][wc2][n2][col] + sred[1][1][wc2][n2][col];
    int kcol = h*128 + (wc2*2+n2)*16 + col;
    sumWA[(size_t)b*NB + kcol] = a;
    sumW [(size_t)b*NB + kcol] = s;
  }
}

// ---------------- loss: per-b block (sims inline), then sum ----------------
__global__ __launch_bounds__(256) void finalize_b2(
    const float* __restrict__ pl,
    const float* __restrict__ sumWA, const float* __restrict__ sumW,
    float* __restrict__ lossb)
{
  const int b = blockIdx.x, k = threadIdx.x;
  __shared__ float s_red[256];
  __shared__ double s_redd[256];

  float plv = (k<NP)? pl[b*NP+k] : 0.f;
  float pmw = (k<NP)? sigf((plv-0.65f)/0.03f) : 0.f;
  float negw= (k<NP)? 1.0f - sigf((plv-0.40f)/0.03f) : 0.f;
  double rr[4];
  rr[0]=(k<NP)?(double)pmw*(double)plv:0.0;
  rr[1]=(k<NP)?(double)pmw:0.0;
  rr[2]=(k<NP)?(double)negw*(double)plv:0.0;
  rr[3]=(k<NP)?(double)negw:0.0;
  double res[4];
  for (int i=0;i<4;++i){
    __syncthreads();
    s_redd[k]=rr[i];
    __syncthreads();
    for (int s=128;s>0;s>>=1){ if (k<s) s_redd[k]+=s_redd[k+s]; __syncthreads(); }
    res[i]=s_redd[0];
  }
  const float sim1v = (float)(res[0]/res[1]);
  const float sim2v = (float)(res[2]/res[3]);
  __syncthreads();

  const float T = 0.07f;
  float s = sumWA[(size_t)b*NB+k]/sumW[(size_t)b*NB+k];
  if (k==b) s *= -99.0f;
  const float lk = s/T;
  const float l0 = sim1v/T, ll = sim2v/T;
  s_red[k]=lk; __syncthreads();
  for (int st=128;st>0;st>>=1){ if(k<st) s_red[k]=fmaxf(s_red[k],s_red[k+st]); __syncthreads(); }
  const float m = fmaxf(s_red[0], fmaxf(l0,ll));
  __syncthreads();
  double e = (double)expf(lk-m);
  if (k==0) e += (double)expf(l0-m)+(double)expf(ll-m);
  s_redd[k]=e; __syncthreads();
  for (int st=128;st>0;st>>=1){ if(k<st) s_redd[k]+=s_redd[k+st]; __syncthreads(); }
  if (k==0) lossb[b] = -(float)((double)(l0-m) - log(s_redd[0]));
}

__global__ __launch_bounds__(256) void finalize_sum(const float* __restrict__ lossb, float* __restrict__ out_loss)
{
  const int tid = threadIdx.x;
  __shared__ double sr[256];
  sr[tid]=(double)lossb[tid]; __syncthreads();
  for (int st=128;st>0;st>>=1){ if(tid<st) sr[tid]+=sr[tid+st]; __syncthreads(); }
  if (tid==0) out_loss[0]=(float)(sr[0]/256.0);
}

extern "C" void kernel_launch(void* const* d_in, const int* in_sizes, int n_in,
                              void* d_out, int out_size, void* d_ws, size_t ws_size,
                              hipStream_t stream)
{
  const float* img = (const float*)d_in[0];
  const float* aud = (const float*)d_in[1];
  float* out = (float*)d_out;
  float* ws  = (float*)d_ws;

  // ws layout (~142 MB < 149.6 MB proven by R4-R18 runs)
  float* pl    = ws;                                           // 50176 f
  unsigned short* aud_bf = (unsigned short*)(pl + NB*NP);      // 131072 us
  unsigned short* hiT = aud_bf + NB*NC;                        // 256*8*196*64 us (49.0 MB)
  unsigned short* loT = hiT + (size_t)NB*8*PR*64;              // 49.0 MB
  float* G     = (float*)(loT + (size_t)NB*8*PR*64);           // 9,834,496 f (37.5 MB)
  double* ppl  = (double*)(G + (size_t)NB*NP*NP);              // NB*8*196 doubles (3.2 MB)
  double* pcs  = ppl + (size_t)NB*8*NP;                        // 3.2 MB
  float* lossb = (float*)(pcs + (size_t)NB*8*NP);              // 256 f

  // sumWA/sumW overlay the ppl region (dead after loop6, written by simgemm2 afterwards)
  float* sumWA = (float*)ppl;
  float* sumW  = sumWA + NB*NB;

  float* out_loss = out;
  float* out_pl   = out + 1;
  float* out_obj  = out + 1 + NB*NP;

  hipLaunchKernelGGL(convert4_kernel, dim3(NB*8),  dim3(512),  0, stream, img, aud, hiT, loT, aud_bf, ppl, pcs);
  hipLaunchKernelGGL(gram2_kernel,    dim3(NB*2),  dim3(512),  0, stream, hiT, loT, G);
  hipLaunchKernelGGL(loop6_kernel,    dim3(NB),    dim3(1024), 0, stream, ppl, pcs, G, hiT, loT, pl, out_pl, out_obj);
  hipLaunchKernelGGL(simgemm2_kernel, dim3(NB*2),  dim3(512),  0, stream, hiT, aud_bf, sumWA, sumW);
  hipLaunchKernelGGL(finalize_b2,     dim3(NB),    dim3(256),  0, stream, pl, sumWA, sumW, lossb);
  hipLaunchKernelGGL(finalize_sum,    dim3(1),     dim3(256),  0, stream, lossb, out_loss);
}